// Round 1
// baseline (4321.358 us; speedup 1.0000x reference)
//
#include <hip/hip_runtime.h>

// PosLearnedSimulator — fp32 baseline, fused MLP3 blocks.
// N=10000 nodes, E=80000 edges, H=128, L=10 layers.
// ws layout: node[N][128] | edge[E][128] | aggr[N][128] | P[N][256]  (~61.5 MB)

#define NH   128          // hidden width
#define RB   64           // rows (edges/nodes) per block tile
#define TPB  256
#define PADW (NH + 1)     // LDS row stride (pad=1 -> conflict-free-ish)

// ---------------- shared device helpers ----------------

// Stage a 64x128 tile of rows from a row-major [*, 128] matrix into As.
// 32 consecutive lanes cover one row (512B) -> best possible coalescing for gathers.
__device__ __forceinline__ void stage_rows128(
    const float* __restrict__ src, const int* __restrict__ ridx,
    int row_base, int nmax, float (*As)[PADW], int t)
{
  const int esub = t >> 5;            // 0..7
  const int f    = (t & 31) * 4;      // float4 column
  #pragma unroll
  for (int it = 0; it < 8; ++it) {
    const int e = it * 8 + esub;
    int r;
    if (ridx) r = ridx[e];
    else { r = row_base + e; if (r >= nmax) r = nmax - 1; }
    const float4 v = *reinterpret_cast<const float4*>(src + (size_t)r * NH + f);
    As[e][f + 0] = v.x; As[e][f + 1] = v.y; As[e][f + 2] = v.z; As[e][f + 3] = v.w;
  }
}

// Small-K input staging (K=7 or 21), perf-irrelevant.
__device__ __forceinline__ void stage_small(
    const float* __restrict__ src, const int* __restrict__ ridx,
    int row_base, int nmax, int F, float (*As)[PADW], int t)
{
  for (int i = t; i < RB * F; i += TPB) {
    const int e = i / F, f = i - e * F;
    int r;
    if (ridx) r = ridx[e];
    else { r = row_base + e; if (r >= nmax) r = nmax - 1; }
    As[e][f] = src[(size_t)r * F + f];
  }
}

__device__ __forceinline__ void init_acc(const float* __restrict__ b, float acc[4][8], int t)
{
  const int o0 = (t >> 4) * 8;
  const float4 c0 = *reinterpret_cast<const float4*>(b + o0);
  const float4 c1 = *reinterpret_cast<const float4*>(b + o0 + 4);
  #pragma unroll
  for (int i = 0; i < 4; ++i) {
    acc[i][0] = c0.x; acc[i][1] = c0.y; acc[i][2] = c0.z; acc[i][3] = c0.w;
    acc[i][4] = c1.x; acc[i][5] = c1.y; acc[i][6] = c1.z; acc[i][7] = c1.w;
  }
}

__device__ __forceinline__ void zero_acc(float acc[4][8])
{
  #pragma unroll
  for (int i = 0; i < 4; ++i)
    #pragma unroll
    for (int j = 0; j < 8; ++j) acc[i][j] = 0.f;
}

#define ROWFMA(i, a) \
  acc[i][0] += (a) * b0.x; acc[i][1] += (a) * b0.y; acc[i][2] += (a) * b0.z; acc[i][3] += (a) * b0.w; \
  acc[i][4] += (a) * b1.x; acc[i][5] += (a) * b1.y; acc[i][6] += (a) * b1.z; acc[i][7] += (a) * b1.w;

// One GEMM over the 128-wide part currently held in As (cols [0,Kpart)),
// W row-major [Kpart][128], streamed through Bs in 32-row chunks.
__device__ __forceinline__ void gemm_block(
    const float* __restrict__ W, int Kpart,
    float (*As)[PADW], float (*Bs)[NH], float acc[4][8], int t)
{
  const int e0 = (t & 15) * 4;
  const int o0 = (t >> 4) * 8;
  for (int sub = 0; sub < Kpart; sub += 32) {
    int kmax = Kpart - sub; if (kmax > 32) kmax = 32;
    __syncthreads();                       // protect Bs (and freshly staged As on first pass)
    {
      const int r  = t >> 3;               // 0..31
      const int f0 = (t & 7) * 16;
      if (r < kmax) {
        const float4* s4 = reinterpret_cast<const float4*>(W + (size_t)(sub + r) * NH + f0);
        float4* d4 = reinterpret_cast<float4*>(&Bs[r][f0]);
        #pragma unroll
        for (int c = 0; c < 4; ++c) d4[c] = s4[c];
      }
    }
    __syncthreads();
    if (kmax == 32) {
      #pragma unroll 8
      for (int k = 0; k < 32; ++k) {
        const int kk = sub + k;
        const float a0 = As[e0 + 0][kk];
        const float a1 = As[e0 + 1][kk];
        const float a2 = As[e0 + 2][kk];
        const float a3 = As[e0 + 3][kk];
        const float4 b0 = *reinterpret_cast<const float4*>(&Bs[k][o0]);
        const float4 b1 = *reinterpret_cast<const float4*>(&Bs[k][o0 + 4]);
        ROWFMA(0, a0) ROWFMA(1, a1) ROWFMA(2, a2) ROWFMA(3, a3)
      }
    } else {
      for (int k = 0; k < kmax; ++k) {
        const int kk = sub + k;
        const float a0 = As[e0 + 0][kk];
        const float a1 = As[e0 + 1][kk];
        const float a2 = As[e0 + 2][kk];
        const float a3 = As[e0 + 3][kk];
        const float4 b0 = *reinterpret_cast<const float4*>(&Bs[k][o0]);
        const float4 b1 = *reinterpret_cast<const float4*>(&Bs[k][o0 + 4]);
        ROWFMA(0, a0) ROWFMA(1, a1) ROWFMA(2, a2) ROWFMA(3, a3)
      }
    }
  }
}

// LeakyReLU(0.01) + write h back into As for the next GEMM stage.
__device__ __forceinline__ void act_store(float (*As)[PADW], float acc[4][8], int t)
{
  const int e0 = (t & 15) * 4;
  const int o0 = (t >> 4) * 8;
  __syncthreads();                         // all reads of As complete
  #pragma unroll
  for (int i = 0; i < 4; ++i)
    #pragma unroll
    for (int j = 0; j < 8; ++j) {
      float v = acc[i][j];
      v = v > 0.f ? v : 0.01f * v;
      As[e0 + i][o0 + j] = v;
    }
  __syncthreads();
}

// ---------------- kernels ----------------

__global__ void __launch_bounds__(TPB) k_enc_node(
    const int* __restrict__ xt, const float* __restrict__ embed,
    const float* __restrict__ W1, const float* __restrict__ b1,
    const float* __restrict__ W2, const float* __restrict__ b2,
    const float* __restrict__ W3, const float* __restrict__ b3,
    float* __restrict__ node, int n)
{
  __shared__ float As[RB][PADW];
  __shared__ float Bs[32][NH];
  __shared__ int rid[RB];
  const int t = threadIdx.x;
  const int base = blockIdx.x * RB;
  if (t < RB) { const int r = base + t; rid[t] = (r < n) ? xt[r] : 0; }
  __syncthreads();
  stage_small(embed, rid, 0, 2, 7, As, t);
  float acc[4][8];
  init_acc(b1, acc, t);
  gemm_block(W1, 7, As, Bs, acc, t);
  act_store(As, acc, t);
  init_acc(b2, acc, t);
  gemm_block(W2, NH, As, Bs, acc, t);
  act_store(As, acc, t);
  init_acc(b3, acc, t);
  gemm_block(W3, NH, As, Bs, acc, t);
  const int e0 = (t & 15) * 4, o0 = (t >> 4) * 8;
  #pragma unroll
  for (int i = 0; i < 4; ++i) {
    const int r = base + e0 + i;
    if (r < n) {
      float4 v0 = {acc[i][0], acc[i][1], acc[i][2], acc[i][3]};
      float4 v1 = {acc[i][4], acc[i][5], acc[i][6], acc[i][7]};
      float4* p = reinterpret_cast<float4*>(node + (size_t)r * NH + o0);
      p[0] = v0; p[1] = v1;
    }
  }
}

__global__ void __launch_bounds__(TPB) k_enc_edge(
    const float* __restrict__ ea,
    const float* __restrict__ W1, const float* __restrict__ b1,
    const float* __restrict__ W2, const float* __restrict__ b2,
    const float* __restrict__ W3, const float* __restrict__ b3,
    float* __restrict__ edge, int n)
{
  __shared__ float As[RB][PADW];
  __shared__ float Bs[32][NH];
  const int t = threadIdx.x;
  const int base = blockIdx.x * RB;
  stage_small(ea, nullptr, base, n, 21, As, t);
  float acc[4][8];
  init_acc(b1, acc, t);
  gemm_block(W1, 21, As, Bs, acc, t);
  act_store(As, acc, t);
  init_acc(b2, acc, t);
  gemm_block(W2, NH, As, Bs, acc, t);
  act_store(As, acc, t);
  init_acc(b3, acc, t);
  gemm_block(W3, NH, As, Bs, acc, t);
  const int e0 = (t & 15) * 4, o0 = (t >> 4) * 8;
  #pragma unroll
  for (int i = 0; i < 4; ++i) {
    const int r = base + e0 + i;
    if (r < n) {
      float4 v0 = {acc[i][0], acc[i][1], acc[i][2], acc[i][3]};
      float4 v1 = {acc[i][4], acc[i][5], acc[i][6], acc[i][7]};
      float4* p = reinterpret_cast<float4*>(edge + (size_t)r * NH + o0);
      p[0] = v0; p[1] = v1;
    }
  }
}

// Per-node precompute of the linear (dst/src) parts of the message-MLP layer 1:
// P[n][0:128] = node[n] @ W1[0:128], P[n][128:256] = node[n] @ W1[128:256]  (no bias)
__global__ void __launch_bounds__(TPB) k_premsg(
    const float* __restrict__ node, const float* __restrict__ W1,
    float* __restrict__ P, int n)
{
  const int part = blockIdx.y;            // 0 = dst-part, 1 = src-part
  __shared__ float As[RB][PADW];
  __shared__ float Bs[32][NH];
  const int t = threadIdx.x;
  const int base = blockIdx.x * RB;
  stage_rows128(node, nullptr, base, n, As, t);
  float acc[4][8];
  zero_acc(acc);
  gemm_block(W1 + (size_t)part * NH * NH, NH, As, Bs, acc, t);
  const int e0 = (t & 15) * 4, o0 = (t >> 4) * 8;
  #pragma unroll
  for (int i = 0; i < 4; ++i) {
    const int r = base + e0 + i;
    if (r < n) {
      float4 v0 = {acc[i][0], acc[i][1], acc[i][2], acc[i][3]};
      float4 v1 = {acc[i][4], acc[i][5], acc[i][6], acc[i][7]};
      float4* p = reinterpret_cast<float4*>(P + (size_t)r * 256 + part * NH + o0);
      p[0] = v0; p[1] = v1;
    }
  }
}

// Message kernel: acc = b1 + P_dst[dst] + P_src[src] + edge@W1c; 2 more GEMMs;
// epilogue: edge += m (in place, own rows) and atomic scatter of m*node_dist onto aggr[dst].
__global__ void __launch_bounds__(TPB) k_msg(
    const int* __restrict__ ei, const float* __restrict__ P,
    float* __restrict__ edge, const float* __restrict__ dist,
    float* __restrict__ aggr,
    const float* __restrict__ W1c, const float* __restrict__ b1,
    const float* __restrict__ W2, const float* __restrict__ b2,
    const float* __restrict__ W3, const float* __restrict__ b3,
    int E)
{
  __shared__ float As[RB][PADW];
  __shared__ float Bs[32][NH];
  __shared__ int sdst[RB];
  __shared__ int ssrc[RB];
  __shared__ float sw[RB];
  const int t = threadIdx.x;
  const int base = blockIdx.x * RB;
  if (t < RB) {
    ssrc[t] = ei[base + t];               // edge_index[0] = source (j)
    sdst[t] = ei[E + base + t];           // edge_index[1] = target (i)
    sw[t]   = dist[base + t];
  }
  __syncthreads();
  stage_rows128(edge, nullptr, base, E, As, t);
  float acc[4][8];
  init_acc(b1, acc, t);
  const int e0 = (t & 15) * 4, o0 = (t >> 4) * 8;
  #pragma unroll
  for (int i = 0; i < 4; ++i) {
    const int e = e0 + i;
    const float* pa = P + (size_t)sdst[e] * 256 + o0;        // dst-part
    const float* pb = P + (size_t)ssrc[e] * 256 + NH + o0;   // src-part
    const float4 a0 = *reinterpret_cast<const float4*>(pa);
    const float4 a1 = *reinterpret_cast<const float4*>(pa + 4);
    const float4 c0 = *reinterpret_cast<const float4*>(pb);
    const float4 c1 = *reinterpret_cast<const float4*>(pb + 4);
    acc[i][0] += a0.x + c0.x; acc[i][1] += a0.y + c0.y;
    acc[i][2] += a0.z + c0.z; acc[i][3] += a0.w + c0.w;
    acc[i][4] += a1.x + c1.x; acc[i][5] += a1.y + c1.y;
    acc[i][6] += a1.z + c1.z; acc[i][7] += a1.w + c1.w;
  }
  gemm_block(W1c, NH, As, Bs, acc, t);
  act_store(As, acc, t);
  init_acc(b2, acc, t);
  gemm_block(W2, NH, As, Bs, acc, t);
  act_store(As, acc, t);
  init_acc(b3, acc, t);
  gemm_block(W3, NH, As, Bs, acc, t);
  // epilogue: m = acc
  #pragma unroll
  for (int i = 0; i < 4; ++i) {
    const int e = e0 + i;
    const int eg = base + e;
    float4* ep = reinterpret_cast<float4*>(edge + (size_t)eg * NH + o0);
    float4 x0 = ep[0], x1 = ep[1];
    x0.x += acc[i][0]; x0.y += acc[i][1]; x0.z += acc[i][2]; x0.w += acc[i][3];
    x1.x += acc[i][4]; x1.y += acc[i][5]; x1.z += acc[i][6]; x1.w += acc[i][7];
    ep[0] = x0; ep[1] = x1;
    const float w = sw[e];
    float* ap = aggr + (size_t)sdst[e] * NH + o0;
    #pragma unroll
    for (int j = 0; j < 8; ++j) atomicAdd(ap + j, acc[i][j] * w);
  }
}

// Node update: node += MLP(cat(node, aggr))
__global__ void __launch_bounds__(TPB) k_node(
    const float* __restrict__ aggr, float* __restrict__ node,
    const float* __restrict__ W1, const float* __restrict__ b1,
    const float* __restrict__ W2, const float* __restrict__ b2,
    const float* __restrict__ W3, const float* __restrict__ b3,
    int n)
{
  __shared__ float As[RB][PADW];
  __shared__ float Bs[32][NH];
  const int t = threadIdx.x;
  const int base = blockIdx.x * RB;
  stage_rows128(node, nullptr, base, n, As, t);
  float acc[4][8];
  init_acc(b1, acc, t);
  gemm_block(W1, NH, As, Bs, acc, t);              // node part (rows 0..127)
  __syncthreads();
  stage_rows128(aggr, nullptr, base, n, As, t);
  gemm_block(W1 + (size_t)NH * NH, NH, As, Bs, acc, t);  // aggr part (rows 128..255)
  act_store(As, acc, t);
  init_acc(b2, acc, t);
  gemm_block(W2, NH, As, Bs, acc, t);
  act_store(As, acc, t);
  init_acc(b3, acc, t);
  gemm_block(W3, NH, As, Bs, acc, t);
  const int e0 = (t & 15) * 4, o0 = (t >> 4) * 8;
  #pragma unroll
  for (int i = 0; i < 4; ++i) {
    const int r = base + e0 + i;
    if (r < n) {
      float4* p = reinterpret_cast<float4*>(node + (size_t)r * NH + o0);
      float4 x0 = p[0], x1 = p[1];
      x0.x += acc[i][0]; x0.y += acc[i][1]; x0.z += acc[i][2]; x0.w += acc[i][3];
      x1.x += acc[i][4]; x1.y += acc[i][5]; x1.z += acc[i][6]; x1.w += acc[i][7];
      p[0] = x0; p[1] = x1;
    }
  }
}

// Decoder: out[n][0:2] = MLP(node) with 2-wide final layer.
__global__ void __launch_bounds__(TPB) k_dec(
    const float* __restrict__ node,
    const float* __restrict__ W1, const float* __restrict__ b1,
    const float* __restrict__ W2, const float* __restrict__ b2,
    const float* __restrict__ W3, const float* __restrict__ b3,
    float* __restrict__ out, int n)
{
  __shared__ float As[RB][PADW];
  __shared__ float Bs[32][NH];
  const int t = threadIdx.x;
  const int base = blockIdx.x * RB;
  stage_rows128(node, nullptr, base, n, As, t);
  float acc[4][8];
  init_acc(b1, acc, t);
  gemm_block(W1, NH, As, Bs, acc, t);
  act_store(As, acc, t);
  init_acc(b2, acc, t);
  gemm_block(W2, NH, As, Bs, acc, t);
  act_store(As, acc, t);                 // h2 now in As
  if (t < RB * 2) {
    const int e = t >> 1, oc = t & 1;
    const int r = base + e;
    if (r < n) {
      float s = b3[oc];
      #pragma unroll 8
      for (int k = 0; k < NH; ++k) s += As[e][k] * W3[k * 2 + oc];
      out[(size_t)r * 2 + oc] = s;
    }
  }
}

// ---------------- host launcher ----------------

extern "C" void kernel_launch(void* const* d_in, const int* in_sizes, int n_in,
                              void* d_out, int out_size, void* d_ws, size_t ws_size,
                              hipStream_t stream)
{
  const int n = in_sizes[0];          // N nodes
  const int E = in_sizes[3];          // node_dist has E elements
  const int* xt        = (const int*)d_in[0];
  const int* ei        = (const int*)d_in[1];
  const float* eattr   = (const float*)d_in[2];
  const float* dist    = (const float*)d_in[3];
  const float* embed   = (const float*)d_in[4];
  const float* niW1 = (const float*)d_in[5];  const float* nib1 = (const float*)d_in[6];
  const float* niW2 = (const float*)d_in[7];  const float* nib2 = (const float*)d_in[8];
  const float* niW3 = (const float*)d_in[9];  const float* nib3 = (const float*)d_in[10];
  const float* eiW1 = (const float*)d_in[11]; const float* eib1 = (const float*)d_in[12];
  const float* eiW2 = (const float*)d_in[13]; const float* eib2 = (const float*)d_in[14];
  const float* eiW3 = (const float*)d_in[15]; const float* eib3 = (const float*)d_in[16];
  const float* noW1 = (const float*)d_in[17]; const float* nob1 = (const float*)d_in[18];
  const float* noW2 = (const float*)d_in[19]; const float* nob2 = (const float*)d_in[20];
  const float* noW3 = (const float*)d_in[21]; const float* nob3 = (const float*)d_in[22];
  const float* meW1 = (const float*)d_in[23]; const float* meb1 = (const float*)d_in[24];
  const float* meW2 = (const float*)d_in[25]; const float* meb2 = (const float*)d_in[26];
  const float* meW3 = (const float*)d_in[27]; const float* meb3 = (const float*)d_in[28];
  const float* mnW1 = (const float*)d_in[29]; const float* mnb1 = (const float*)d_in[30];
  const float* mnW2 = (const float*)d_in[31]; const float* mnb2 = (const float*)d_in[32];
  const float* mnW3 = (const float*)d_in[33]; const float* mnb3 = (const float*)d_in[34];

  float* out  = (float*)d_out;
  float* node = (float*)d_ws;                       // N*128
  float* edge = node + (size_t)n * NH;              // E*128
  float* aggr = edge + (size_t)E * NH;              // N*128
  float* P    = aggr + (size_t)n * NH;              // N*256

  const int nb_n = (n + RB - 1) / RB;
  const int nb_e = (E + RB - 1) / RB;

  k_enc_node<<<nb_n, TPB, 0, stream>>>(xt, embed, niW1, nib1, niW2, nib2, niW3, nib3, node, n);
  k_enc_edge<<<nb_e, TPB, 0, stream>>>(eattr, eiW1, eib1, eiW2, eib2, eiW3, eib3, edge, E);

  for (int l = 0; l < 10; ++l) {
    hipMemsetAsync(aggr, 0, (size_t)n * NH * sizeof(float), stream);
    k_premsg<<<dim3(nb_n, 2), TPB, 0, stream>>>(node, meW1 + (size_t)l * 384 * NH, P, n);
    k_msg<<<nb_e, TPB, 0, stream>>>(ei, P, edge, dist, aggr,
        meW1 + (size_t)l * 384 * NH + (size_t)256 * NH, meb1 + (size_t)l * NH,
        meW2 + (size_t)l * NH * NH,                    meb2 + (size_t)l * NH,
        meW3 + (size_t)l * NH * NH,                    meb3 + (size_t)l * NH, E);
    k_node<<<nb_n, TPB, 0, stream>>>(aggr, node,
        mnW1 + (size_t)l * 256 * NH, mnb1 + (size_t)l * NH,
        mnW2 + (size_t)l * NH * NH,  mnb2 + (size_t)l * NH,
        mnW3 + (size_t)l * NH * NH,  mnb3 + (size_t)l * NH, n);
  }

  k_dec<<<nb_n, TPB, 0, stream>>>(node, noW1, nob1, noW2, nob2, noW3, nob3, out, n);
}

// Round 2
// 2256.217 us; speedup vs baseline: 1.9153x; 1.9153x over previous
//
#include <hip/hip_runtime.h>

// PosLearnedSimulator — fp32, fused MLP3 blocks, CSR aggregation (no steady-state atomics).
// N=10000 nodes, E=80000 edges, H=128, L=10 layers.

#define NH  128
#define TPB 256

// ---------------- LDS swizzle helpers ----------------
// As: [RB][128] floats, stored as 16B chunks; chunk ch of row r lives at chunk slot ch ^ ((r>>2)&7).
// Bs: [32][128] floats; chunk c of a row lives at slot c ^ ((c>>3)&1)  (spreads the 8-wide column
//     groups across odd/even bank quads).
__device__ __forceinline__ int swzB(int c) { return c ^ ((c >> 3) & 1); }

__device__ __forceinline__ float lrelu(float v) { return v > 0.f ? v : 0.01f * v; }

__device__ __forceinline__ void fma8(float* a, float s, const float4 b0, const float4 b1) {
  a[0] += s * b0.x; a[1] += s * b0.y; a[2] += s * b0.z; a[3] += s * b0.w;
  a[4] += s * b1.x; a[5] += s * b1.y; a[6] += s * b1.z; a[7] += s * b1.w;
}

// Stage RB rows of a row-major [*,128] f32 matrix into swizzled As. 32 lanes cover one row.
template<int RB>
__device__ __forceinline__ void stage_rows128(
    const float* __restrict__ src, int row_base, int nmax, float* As, int t)
{
  const int c = t & 31;                  // 16B chunk index 0..31
  for (int e = t >> 5; e < RB; e += 8) {
    int r = row_base + e; if (r >= nmax) r = nmax - 1;
    const float4 v = reinterpret_cast<const float4*>(src + (size_t)r * NH)[c];
    reinterpret_cast<float4*>(As)[e * 32 + (c ^ ((e >> 2) & 7))] = v;
  }
}

// Small-K staging (K=7 or 21), scalar, swizzled. One-shot kernels only.
template<int RB>
__device__ __forceinline__ void stage_smallK(
    const float* __restrict__ src, const int* __restrict__ ridx,
    int row_base, int nmax, int F, float* As, int t)
{
  for (int i = t; i < RB * F; i += TPB) {
    const int e = i / F, f = i - e * F;
    int r;
    if (ridx) r = ridx[e];
    else { r = row_base + e; if (r >= nmax) r = nmax - 1; }
    As[e * NH + ((((f >> 2) ^ ((e >> 2) & 7)) << 2) | (f & 3))] = src[(size_t)r * F + f];
  }
}

template<int AR>
__device__ __forceinline__ void init_acc(const float* __restrict__ b, float acc[AR][8], int t)
{
  const int o0 = (t >> 4) * 8;
  const float4 c0 = *reinterpret_cast<const float4*>(b + o0);
  const float4 c1 = *reinterpret_cast<const float4*>(b + o0 + 4);
  #pragma unroll
  for (int i = 0; i < AR; ++i) {
    acc[i][0] = c0.x; acc[i][1] = c0.y; acc[i][2] = c0.z; acc[i][3] = c0.w;
    acc[i][4] = c1.x; acc[i][5] = c1.y; acc[i][6] = c1.z; acc[i][7] = c1.w;
  }
}

template<int AR>
__device__ __forceinline__ void zero_acc(float acc[AR][8])
{
  #pragma unroll
  for (int i = 0; i < AR; ++i)
    #pragma unroll
    for (int j = 0; j < 8; ++j) acc[i][j] = 0.f;
}

// GEMM over cols [0,Kpart) of swizzled As; W row-major [Kpart][128] streamed via Bs.
// Thread tile: AR rows x 8 cols; rows e0=(t&15)*AR.., cols o0=(t>>4)*8..
template<int AR>
__device__ __forceinline__ void gemm_block(
    const float* __restrict__ W, int Kpart,
    const float* As, float* Bs, float acc[AR][8], int t)
{
  const int e0  = (t & 15) * AR;
  const int g   = t >> 4;
  const int ob0 = swzB(g * 2) * 4;
  const int ob1 = swzB(g * 2 + 1) * 4;
  int sr[AR];
  #pragma unroll
  for (int i = 0; i < AR; ++i) sr[i] = ((e0 + i) >> 2) & 7;

  for (int sub = 0; sub < Kpart; sub += 32) {
    int kmax = Kpart - sub; if (kmax > 32) kmax = 32;
    __syncthreads();                     // Bs reuse (and As freshly staged on first pass)
    {
      const int r  = t >> 3;             // 0..31
      const int cb = (t & 7) * 4;        // chunk base
      if (r < kmax) {
        const float4* s4 = reinterpret_cast<const float4*>(W + (size_t)(sub + r) * NH) + cb;
        #pragma unroll
        for (int j = 0; j < 4; ++j)
          *reinterpret_cast<float4*>(Bs + r * NH + swzB(cb + j) * 4) = s4[j];
      }
    }
    __syncthreads();
    if (kmax == 32) {
      #pragma unroll
      for (int k4 = 0; k4 < 8; ++k4) {
        const int gch = (sub >> 2) + k4;
        float4 aa[AR];
        #pragma unroll
        for (int i = 0; i < AR; ++i)
          aa[i] = reinterpret_cast<const float4*>(As)[(e0 + i) * 32 + (gch ^ sr[i])];
        #pragma unroll
        for (int kk = 0; kk < 4; ++kk) {
          const int k = k4 * 4 + kk;
          const float4 b0 = *reinterpret_cast<const float4*>(Bs + k * NH + ob0);
          const float4 b1 = *reinterpret_cast<const float4*>(Bs + k * NH + ob1);
          #pragma unroll
          for (int i = 0; i < AR; ++i) {
            const float a = (kk == 0) ? aa[i].x : (kk == 1) ? aa[i].y : (kk == 2) ? aa[i].z : aa[i].w;
            fma8(acc[i], a, b0, b1);
          }
        }
      }
    } else {
      for (int k = 0; k < kmax; ++k) {
        const int kk = sub + k;
        const float4 b0 = *reinterpret_cast<const float4*>(Bs + k * NH + ob0);
        const float4 b1 = *reinterpret_cast<const float4*>(Bs + k * NH + ob1);
        #pragma unroll
        for (int i = 0; i < AR; ++i) {
          const float a = As[(e0 + i) * NH + ((((kk >> 2) ^ sr[i]) << 2) | (kk & 3))];
          fma8(acc[i], a, b0, b1);
        }
      }
    }
  }
}

// LeakyReLU (optional) + write acc back into swizzled As (two b128 per row).
template<int AR, bool ACT>
__device__ __forceinline__ void act_store(float* As, float acc[AR][8], int t)
{
  const int e0 = (t & 15) * AR;
  const int g  = t >> 4;
  __syncthreads();                       // all reads of As complete
  #pragma unroll
  for (int i = 0; i < AR; ++i) {
    const int r = e0 + i;
    const int s = (r >> 2) & 7;
    float v[8];
    #pragma unroll
    for (int j = 0; j < 8; ++j) v[j] = ACT ? lrelu(acc[i][j]) : acc[i][j];
    float4 w0 = {v[0], v[1], v[2], v[3]};
    float4 w1 = {v[4], v[5], v[6], v[7]};
    reinterpret_cast<float4*>(As + r * NH)[(g * 2)     ^ s] = w0;
    reinterpret_cast<float4*>(As + r * NH)[(g * 2 + 1) ^ s] = w1;
  }
  __syncthreads();
}

// ---------------- CSR build ----------------

__global__ void __launch_bounds__(256) k_deg(const int* __restrict__ dst, int* __restrict__ cnt, int E)
{
  const int e = blockIdx.x * 256 + threadIdx.x;
  if (e < E) atomicAdd(&cnt[dst[e]], 1);
}

__global__ void __launch_bounds__(256) k_scan(int* __restrict__ cur, int* __restrict__ off, int n, int E)
{
  __shared__ int ps[256];
  const int t = threadIdx.x;
  const int chunk = (n + 255) / 256;
  const int b0 = t * chunk;
  int s = 0;
  for (int j = 0; j < chunk; ++j) { const int r = b0 + j; if (r < n) s += cur[r]; }
  ps[t] = s; __syncthreads();
  for (int d = 1; d < 256; d <<= 1) {
    const int v = (t >= d) ? ps[t - d] : 0; __syncthreads();
    ps[t] += v; __syncthreads();
  }
  int run = ps[t] - s;                   // exclusive prefix
  for (int j = 0; j < chunk; ++j) {
    const int r = b0 + j;
    if (r < n) { const int d = cur[r]; off[r] = run; cur[r] = run; run += d; }
  }
  if (t == 0) off[n] = E;
}

__global__ void __launch_bounds__(256) k_fill(const int* __restrict__ dst, int* __restrict__ cur,
                                              int* __restrict__ csr, int E)
{
  const int e = blockIdx.x * 256 + threadIdx.x;
  if (e < E) { const int p = atomicAdd(&cur[dst[e]], 1); csr[p] = e; }
}

// ---------------- kernels ----------------

__global__ void __launch_bounds__(TPB) k_enc_node(
    const int* __restrict__ xt, const float* __restrict__ embed,
    const float* __restrict__ W1, const float* __restrict__ b1,
    const float* __restrict__ W2, const float* __restrict__ b2,
    const float* __restrict__ W3, const float* __restrict__ b3,
    float* __restrict__ node, int n)
{
  constexpr int RB = 32, AR = 2;
  __shared__ float As[RB * NH];
  __shared__ float Bs[32 * NH];
  __shared__ int rid[RB];
  const int t = threadIdx.x;
  const int base = blockIdx.x * RB;
  if (t < RB) { int r = base + t; if (r >= n) r = n - 1; rid[t] = xt[r]; }
  __syncthreads();
  stage_smallK<RB>(embed, rid, 0, 2, 7, As, t);
  float acc[AR][8];
  init_acc<AR>(b1, acc, t);
  gemm_block<AR>(W1, 7, As, Bs, acc, t);
  act_store<AR, true>(As, acc, t);
  init_acc<AR>(b2, acc, t);
  gemm_block<AR>(W2, NH, As, Bs, acc, t);
  act_store<AR, true>(As, acc, t);
  init_acc<AR>(b3, acc, t);
  gemm_block<AR>(W3, NH, As, Bs, acc, t);
  const int e0 = (t & 15) * AR, o0 = (t >> 4) * 8;
  #pragma unroll
  for (int i = 0; i < AR; ++i) {
    const int r = base + e0 + i;
    if (r < n) {
      float4 v0 = {acc[i][0], acc[i][1], acc[i][2], acc[i][3]};
      float4 v1 = {acc[i][4], acc[i][5], acc[i][6], acc[i][7]};
      float4* p = reinterpret_cast<float4*>(node + (size_t)r * NH + o0);
      p[0] = v0; p[1] = v1;
    }
  }
}

__global__ void __launch_bounds__(TPB) k_enc_edge(
    const float* __restrict__ ea,
    const float* __restrict__ W1, const float* __restrict__ b1,
    const float* __restrict__ W2, const float* __restrict__ b2,
    const float* __restrict__ W3, const float* __restrict__ b3,
    float* __restrict__ edge, int nE)
{
  constexpr int RB = 64, AR = 4;
  __shared__ float As[RB * NH];
  __shared__ float Bs[32 * NH];
  const int t = threadIdx.x;
  const int base = blockIdx.x * RB;
  stage_smallK<RB>(ea, nullptr, base, nE, 21, As, t);
  float acc[AR][8];
  init_acc<AR>(b1, acc, t);
  gemm_block<AR>(W1, 21, As, Bs, acc, t);
  act_store<AR, true>(As, acc, t);
  init_acc<AR>(b2, acc, t);
  gemm_block<AR>(W2, NH, As, Bs, acc, t);
  act_store<AR, true>(As, acc, t);
  init_acc<AR>(b3, acc, t);
  gemm_block<AR>(W3, NH, As, Bs, acc, t);
  const int e0 = (t & 15) * AR, o0 = (t >> 4) * 8;
  #pragma unroll
  for (int i = 0; i < AR; ++i) {
    const int r = base + e0 + i;
    if (r < nE) {
      float4 v0 = {acc[i][0], acc[i][1], acc[i][2], acc[i][3]};
      float4 v1 = {acc[i][4], acc[i][5], acc[i][6], acc[i][7]};
      float4* p = reinterpret_cast<float4*>(edge + (size_t)r * NH + o0);
      p[0] = v0; p[1] = v1;
    }
  }
}

// P[n][0:128] = node@W1[0:128] (dst part), P[n][128:256] = node@W1[128:256] (src part); no bias.
__global__ void __launch_bounds__(TPB) k_premsg(
    const float* __restrict__ node, const float* __restrict__ W1,
    float* __restrict__ P, int n)
{
  constexpr int RB = 32, AR = 2;
  const int part = blockIdx.y;
  __shared__ float As[RB * NH];
  __shared__ float Bs[32 * NH];
  const int t = threadIdx.x;
  const int base = blockIdx.x * RB;
  stage_rows128<RB>(node, base, n, As, t);
  float acc[AR][8];
  zero_acc<AR>(acc);
  gemm_block<AR>(W1 + (size_t)part * NH * NH, NH, As, Bs, acc, t);
  const int e0 = (t & 15) * AR, o0 = (t >> 4) * 8;
  #pragma unroll
  for (int i = 0; i < AR; ++i) {
    const int r = base + e0 + i;
    if (r < n) {
      float4 v0 = {acc[i][0], acc[i][1], acc[i][2], acc[i][3]};
      float4 v1 = {acc[i][4], acc[i][5], acc[i][6], acc[i][7]};
      float4* p = reinterpret_cast<float4*>(P + (size_t)r * 256 + part * NH + o0);
      p[0] = v0; p[1] = v1;
    }
  }
}

// m = MLP(cat via P + edge@W1c); edge += m; CSR: mout[e] = m*dist  |  ATOMIC: scatter-add.
template<bool ATOMIC>
__global__ void __launch_bounds__(TPB) k_msg(
    const int* __restrict__ ei, const float* __restrict__ P,
    float* __restrict__ edge, const float* __restrict__ dist,
    float* __restrict__ mout,
    const float* __restrict__ W1c, const float* __restrict__ b1,
    const float* __restrict__ W2, const float* __restrict__ b2,
    const float* __restrict__ W3, const float* __restrict__ b3,
    int E)
{
  constexpr int RB = 64, AR = 4;
  __shared__ float As[RB * NH];
  __shared__ float Bs[32 * NH];
  __shared__ int sdst[RB];
  __shared__ int ssrc[RB];
  __shared__ float sw[RB];
  const int t = threadIdx.x;
  const int base = blockIdx.x * RB;
  if (t < RB) {
    int e = base + t; if (e >= E) e = E - 1;
    ssrc[t] = ei[e];                    // edge_index[0] = source (j)
    sdst[t] = ei[E + e];                // edge_index[1] = target (i)
    sw[t]   = dist[e];
  }
  __syncthreads();
  stage_rows128<RB>(edge, base, E, As, t);
  float acc[AR][8];
  init_acc<AR>(b1, acc, t);
  const int e0 = (t & 15) * AR, o0 = (t >> 4) * 8;
  #pragma unroll
  for (int i = 0; i < AR; ++i) {
    const int e = e0 + i;
    const float* pa = P + (size_t)sdst[e] * 256 + o0;        // dst part
    const float* pb = P + (size_t)ssrc[e] * 256 + NH + o0;   // src part
    const float4 a0 = *reinterpret_cast<const float4*>(pa);
    const float4 a1 = *reinterpret_cast<const float4*>(pa + 4);
    const float4 c0 = *reinterpret_cast<const float4*>(pb);
    const float4 c1 = *reinterpret_cast<const float4*>(pb + 4);
    acc[i][0] += a0.x + c0.x; acc[i][1] += a0.y + c0.y;
    acc[i][2] += a0.z + c0.z; acc[i][3] += a0.w + c0.w;
    acc[i][4] += a1.x + c1.x; acc[i][5] += a1.y + c1.y;
    acc[i][6] += a1.z + c1.z; acc[i][7] += a1.w + c1.w;
  }
  gemm_block<AR>(W1c, NH, As, Bs, acc, t);
  act_store<AR, true>(As, acc, t);
  init_acc<AR>(b2, acc, t);
  gemm_block<AR>(W2, NH, As, Bs, acc, t);
  act_store<AR, true>(As, acc, t);
  init_acc<AR>(b3, acc, t);
  gemm_block<AR>(W3, NH, As, Bs, acc, t);
  #pragma unroll
  for (int i = 0; i < AR; ++i) {
    const int e  = e0 + i;
    const int eg = base + e;
    if (eg < E) {
      float4* ep = reinterpret_cast<float4*>(edge + (size_t)eg * NH + o0);
      float4 x0 = ep[0], x1 = ep[1];
      x0.x += acc[i][0]; x0.y += acc[i][1]; x0.z += acc[i][2]; x0.w += acc[i][3];
      x1.x += acc[i][4]; x1.y += acc[i][5]; x1.z += acc[i][6]; x1.w += acc[i][7];
      ep[0] = x0; ep[1] = x1;
      const float w = sw[e];
      if (ATOMIC) {
        float* ap = mout + (size_t)sdst[e] * NH + o0;
        #pragma unroll
        for (int j = 0; j < 8; ++j) atomicAdd(ap + j, acc[i][j] * w);
      } else {
        float4 m0 = {acc[i][0] * w, acc[i][1] * w, acc[i][2] * w, acc[i][3] * w};
        float4 m1 = {acc[i][4] * w, acc[i][5] * w, acc[i][6] * w, acc[i][7] * w};
        float4* mp = reinterpret_cast<float4*>(mout + (size_t)eg * NH + o0);
        mp[0] = m0; mp[1] = m1;
      }
    }
  }
}

// node += MLP(cat(node, aggr)); aggr from CSR gather over mw (GATHER) or from aggr buffer.
template<bool GATHER>
__global__ void __launch_bounds__(TPB) k_node(
    const int* __restrict__ off, const int* __restrict__ csr,
    const float* __restrict__ mw,          // GATHER: mw[E][128] ; else aggr[N][128]
    float* __restrict__ node,
    const float* __restrict__ W1, const float* __restrict__ b1,
    const float* __restrict__ W2, const float* __restrict__ b2,
    const float* __restrict__ W3, const float* __restrict__ b3,
    int n)
{
  constexpr int RB = 32, AR = 2;
  __shared__ float As[RB * NH];
  __shared__ float Bs[32 * NH];
  const int t = threadIdx.x;
  const int base = blockIdx.x * RB;
  stage_rows128<RB>(node, base, n, As, t);
  float acc[AR][8];
  init_acc<AR>(b1, acc, t);
  gemm_block<AR>(W1, NH, As, Bs, acc, t);           // node part (rows 0..127 of W1)
  __syncthreads();                                  // done reading node tile from As
  if (GATHER) {
    // 8 threads per row, 16 floats (4 chunks) each; sum of mw rows listed in CSR.
    const int gr = t >> 3;                          // row 0..31
    const int cb = (t & 7) * 4;                     // chunk base 0..28
    float a[4][4];
    #pragma unroll
    for (int u = 0; u < 4; ++u)
      #pragma unroll
      for (int v = 0; v < 4; ++v) a[u][v] = 0.f;
    const int rg = base + gr;
    if (rg < n) {
      const int eb = off[rg], ee = off[rg + 1];
      for (int ii = eb; ii < ee; ++ii) {
        const int eid = csr[ii];
        const float4* mp = reinterpret_cast<const float4*>(mw + (size_t)eid * NH) + cb;
        #pragma unroll
        for (int u = 0; u < 4; ++u) {
          const float4 x = mp[u];
          a[u][0] += x.x; a[u][1] += x.y; a[u][2] += x.z; a[u][3] += x.w;
        }
      }
    }
    const int s = (gr >> 2) & 7;
    #pragma unroll
    for (int u = 0; u < 4; ++u) {
      float4 w = {a[u][0], a[u][1], a[u][2], a[u][3]};
      reinterpret_cast<float4*>(As + gr * NH)[(cb + u) ^ s] = w;
    }
  } else {
    stage_rows128<RB>(mw, base, n, As, t);          // mw == aggr buffer here
  }
  gemm_block<AR>(W1 + (size_t)NH * NH, NH, As, Bs, acc, t);   // aggr part
  act_store<AR, true>(As, acc, t);
  init_acc<AR>(b2, acc, t);
  gemm_block<AR>(W2, NH, As, Bs, acc, t);
  act_store<AR, true>(As, acc, t);
  init_acc<AR>(b3, acc, t);
  gemm_block<AR>(W3, NH, As, Bs, acc, t);
  const int e0 = (t & 15) * AR, o0 = (t >> 4) * 8;
  #pragma unroll
  for (int i = 0; i < AR; ++i) {
    const int r = base + e0 + i;
    if (r < n) {
      float4* p = reinterpret_cast<float4*>(node + (size_t)r * NH + o0);
      float4 x0 = p[0], x1 = p[1];
      x0.x += acc[i][0]; x0.y += acc[i][1]; x0.z += acc[i][2]; x0.w += acc[i][3];
      x1.x += acc[i][4]; x1.y += acc[i][5]; x1.z += acc[i][6]; x1.w += acc[i][7];
      p[0] = x0; p[1] = x1;
    }
  }
}

__global__ void __launch_bounds__(TPB) k_dec(
    const float* __restrict__ node,
    const float* __restrict__ W1, const float* __restrict__ b1,
    const float* __restrict__ W2, const float* __restrict__ b2,
    const float* __restrict__ W3, const float* __restrict__ b3,
    float* __restrict__ out, int n)
{
  constexpr int RB = 32, AR = 2;
  __shared__ float As[RB * NH];
  __shared__ float Bs[32 * NH];
  const int t = threadIdx.x;
  const int base = blockIdx.x * RB;
  stage_rows128<RB>(node, base, n, As, t);
  float acc[AR][8];
  init_acc<AR>(b1, acc, t);
  gemm_block<AR>(W1, NH, As, Bs, acc, t);
  act_store<AR, true>(As, acc, t);
  init_acc<AR>(b2, acc, t);
  gemm_block<AR>(W2, NH, As, Bs, acc, t);
  act_store<AR, true>(As, acc, t);                 // h2 in As (swizzled)
  if (t < RB * 2) {
    const int e = t >> 1, oc = t & 1;
    const int r = base + e;
    if (r < n) {
      const int s = (e >> 2) & 7;
      float sum = b3[oc];
      #pragma unroll 8
      for (int k = 0; k < NH; ++k)
        sum += As[e * NH + ((((k >> 2) ^ s) << 2) | (k & 3))] * W3[k * 2 + oc];
      out[(size_t)r * 2 + oc] = sum;
    }
  }
}

// ---------------- host launcher ----------------

extern "C" void kernel_launch(void* const* d_in, const int* in_sizes, int n_in,
                              void* d_out, int out_size, void* d_ws, size_t ws_size,
                              hipStream_t stream)
{
  const int n = in_sizes[0];
  const int E = in_sizes[3];
  const int* xt      = (const int*)d_in[0];
  const int* ei      = (const int*)d_in[1];
  const float* eattr = (const float*)d_in[2];
  const float* dist  = (const float*)d_in[3];
  const float* embed = (const float*)d_in[4];
  const float* niW1 = (const float*)d_in[5];  const float* nib1 = (const float*)d_in[6];
  const float* niW2 = (const float*)d_in[7];  const float* nib2 = (const float*)d_in[8];
  const float* niW3 = (const float*)d_in[9];  const float* nib3 = (const float*)d_in[10];
  const float* eiW1 = (const float*)d_in[11]; const float* eib1 = (const float*)d_in[12];
  const float* eiW2 = (const float*)d_in[13]; const float* eib2 = (const float*)d_in[14];
  const float* eiW3 = (const float*)d_in[15]; const float* eib3 = (const float*)d_in[16];
  const float* noW1 = (const float*)d_in[17]; const float* nob1 = (const float*)d_in[18];
  const float* noW2 = (const float*)d_in[19]; const float* nob2 = (const float*)d_in[20];
  const float* noW3 = (const float*)d_in[21]; const float* nob3 = (const float*)d_in[22];
  const float* meW1 = (const float*)d_in[23]; const float* meb1 = (const float*)d_in[24];
  const float* meW2 = (const float*)d_in[25]; const float* meb2 = (const float*)d_in[26];
  const float* meW3 = (const float*)d_in[27]; const float* meb3 = (const float*)d_in[28];
  const float* mnW1 = (const float*)d_in[29]; const float* mnb1 = (const float*)d_in[30];
  const float* mnW2 = (const float*)d_in[31]; const float* mnb2 = (const float*)d_in[32];
  const float* mnW3 = (const float*)d_in[33]; const float* mnb3 = (const float*)d_in[34];

  float* out = (float*)d_out;
  const size_t fn = (size_t)n * NH;
  const size_t fe = (size_t)E * NH;
  const size_t fP = (size_t)n * 256;
  const size_t need_csr = (fn + 2 * fe + fP) * 4 + ((size_t)(2 * n + 1 + E)) * 4;
  const bool use_csr = ws_size >= need_csr;

  float* node = (float*)d_ws;
  float* edge = node + fn;
  float* mw   = edge + fe;                         // CSR: mw[E][128] | fallback: aggr[N][128]
  float* P    = mw + (use_csr ? fe : fn);
  int*   off  = (int*)(P + fP);
  int*   cur  = off + (n + 1);
  int*   csr  = cur + n;

  const int nb32  = (n + 31) / 32;
  const int nb64e = (E + 63) / 64;

  if (use_csr) {
    hipMemsetAsync(cur, 0, (size_t)n * sizeof(int), stream);
    k_deg <<<(E + 255) / 256, 256, 0, stream>>>(ei + E, cur, E);
    k_scan<<<1, 256, 0, stream>>>(cur, off, n, E);
    k_fill<<<(E + 255) / 256, 256, 0, stream>>>(ei + E, cur, csr, E);
  }

  k_enc_node<<<nb32,  TPB, 0, stream>>>(xt, embed, niW1, nib1, niW2, nib2, niW3, nib3, node, n);
  k_enc_edge<<<nb64e, TPB, 0, stream>>>(eattr, eiW1, eib1, eiW2, eib2, eiW3, eib3, edge, E);

  for (int l = 0; l < 10; ++l) {
    const float* W1  = meW1 + (size_t)l * 384 * NH;
    const float* W1c = W1 + (size_t)256 * NH;
    if (!use_csr) hipMemsetAsync(mw, 0, fn * sizeof(float), stream);
    k_premsg<<<dim3(nb32, 2), TPB, 0, stream>>>(node, W1, P, n);
    if (use_csr) {
      k_msg<false><<<nb64e, TPB, 0, stream>>>(ei, P, edge, dist, mw,
          W1c, meb1 + (size_t)l * NH,
          meW2 + (size_t)l * NH * NH, meb2 + (size_t)l * NH,
          meW3 + (size_t)l * NH * NH, meb3 + (size_t)l * NH, E);
      k_node<true><<<nb32, TPB, 0, stream>>>(off, csr, mw, node,
          mnW1 + (size_t)l * 256 * NH, mnb1 + (size_t)l * NH,
          mnW2 + (size_t)l * NH * NH,  mnb2 + (size_t)l * NH,
          mnW3 + (size_t)l * NH * NH,  mnb3 + (size_t)l * NH, n);
    } else {
      k_msg<true><<<nb64e, TPB, 0, stream>>>(ei, P, edge, dist, mw,
          W1c, meb1 + (size_t)l * NH,
          meW2 + (size_t)l * NH * NH, meb2 + (size_t)l * NH,
          meW3 + (size_t)l * NH * NH, meb3 + (size_t)l * NH, E);
      k_node<false><<<nb32, TPB, 0, stream>>>(nullptr, nullptr, mw, node,
          mnW1 + (size_t)l * 256 * NH, mnb1 + (size_t)l * NH,
          mnW2 + (size_t)l * NH * NH,  mnb2 + (size_t)l * NH,
          mnW3 + (size_t)l * NH * NH,  mnb3 + (size_t)l * NH, n);
    }
  }

  k_dec<<<nb32, TPB, 0, stream>>>(node, noW1, nob1, noW2, nob2, noW3, nob3, out, n);
}